// Round 6
// baseline (468.274 us; speedup 1.0000x reference)
//
#include <hip/hip_runtime.h>
#include <stdint.h>

typedef _Float16 half8 __attribute__((ext_vector_type(8)));
typedef float f32x4 __attribute__((ext_vector_type(4)));

#define CIN   256
#define COUT  256
#define NB    32
#define HH    56
#define WW    56
#define WPAD  58
#define HW2   3136            // 56*56
#define KHALF 4608            // 9 * 256 * 2 (hi/lo interleaved)
#define NKT   144             // K-tiles of 32 halves (64B)
#define XQ_BYTES 110231552L   // 32*58*58*256*4
#define WD_BYTES 2359296L     // 256*4608*2

// GEMM geometry: BM=128 (cout half) x BN=112 pixels, 4 waves, grid 1792 = 7/CU exact.
// LDS: 3 x (A 8KB + B 7KB) = 45KB -> 3 blocks/CU co-resident.
#define ABUF(i) ((i) * 8192)
#define BBUF(i) (24576 + (i) * 7168)

__device__ __forceinline__ float quant_fixed(float x) {
  float q = floorf(x * 65536.0f) * (1.0f / 65536.0f);
  return fminf(fmaxf(q, -32768.0f), 32767.0f);
}

__device__ __forceinline__ void gload16(const void* g, void* l) {
  __builtin_amdgcn_global_load_lds(
      (const __attribute__((address_space(1))) void*)g,
      (__attribute__((address_space(3))) void*)l, 16, 0, 0);
}

#define WAIT_LGKM0() do { asm volatile("s_waitcnt lgkmcnt(0)" ::: "memory"); \
                          __builtin_amdgcn_sched_barrier(0); } while (0)
#define BAR() __builtin_amdgcn_s_barrier()

// ---------- weight prep: Wd[cout][k], k = r*512 + cin*2 + {hi,lo}, both slots = v ----------
__global__ void prep_w(const float* __restrict__ shift, const float* __restrict__ sgn,
                       uint32_t* __restrict__ Wd32) {
  int o = blockIdx.x * 256 + threadIdx.x;       // o = cout*2304 + r*256 + cin
  if (o >= COUT * 2304) return;
  int cout = o / 2304;
  int rem  = o % 2304;
  int r    = rem >> 8;
  int cin  = rem & 255;
  int idx  = cout * 2304 + cin * 9 + r;         // OIHW source index
  float s  = rintf(fminf(fmaxf(shift[idx], -14.0f), 0.0f));
  float sg = rintf(sgn[idx]);
  float v  = (sg > 0.0f ? 1.0f : (sg < 0.0f ? -1.0f : 0.0f)) * exp2f(s);
  _Float16 vh = (_Float16)v;
  uint16_t u = __builtin_bit_cast(uint16_t, vh);
  Wd32[o] = ((uint32_t)u << 16) | u;
}

// fp32 weights in OIHW order (fallback path only)
__global__ void prep_w_f32(const float* __restrict__ shift, const float* __restrict__ sgn,
                           float* __restrict__ vw) {
  int idx = blockIdx.x * 256 + threadIdx.x;
  if (idx >= COUT * CIN * 9) return;
  float s  = rintf(fminf(fmaxf(shift[idx], -14.0f), 0.0f));
  float sg = rintf(sgn[idx]);
  vw[idx]  = (sg > 0.0f ? 1.0f : (sg < 0.0f ? -1.0f : 0.0f)) * exp2f(s);
}

// ---------- activation prep: NCHW fp32 -> padded NHWC uint32 (lo<<16 | hi fp16 pair) ----------
// float2 in-loads, uint2 out-stores (G13)
__global__ void prep_x(const float* __restrict__ in, uint32_t* __restrict__ xq) {
  int cinblk = blockIdx.x;   // 0..3  (64 channels each)
  int h      = blockIdx.y;   // 0..55
  int b      = blockIdx.z;   // 0..31
  int t      = threadIdx.x;  // 256
  __shared__ uint32_t lds[64 * 57];
  const float* src = in + ((long)(b * CIN + cinblk * 64)) * HW2 + h * WW;
  #pragma unroll
  for (int i = 0; i < 7; i++) {            // 64ch * 28 wpairs = 1792 = 7*256
    int e = t + i * 256;
    int cin = e / 28, w = (e % 28) * 2;
    float2 x2 = *reinterpret_cast<const float2*>(src + (long)cin * HW2 + w);
    float q0 = quant_fixed(x2.x), q1 = quant_fixed(x2.y);
    _Float16 h0 = (_Float16)q0, l0 = (_Float16)(q0 - (float)h0);
    _Float16 h1 = (_Float16)q1, l1 = (_Float16)(q1 - (float)h1);
    lds[cin * 57 + w]     = ((uint32_t)__builtin_bit_cast(uint16_t, l0) << 16)
                           | __builtin_bit_cast(uint16_t, h0);
    lds[cin * 57 + w + 1] = ((uint32_t)__builtin_bit_cast(uint16_t, l1) << 16)
                           | __builtin_bit_cast(uint16_t, h1);
  }
  __syncthreads();
  uint32_t* dst = xq + ((long)(b * WPAD + h + 1) * WPAD + 1) * CIN + cinblk * 64;
  #pragma unroll
  for (int i = 0; i < 7; i++) {            // 56 w * 32 cpairs = 1792
    int e = t + i * 256;
    int w = e >> 5, cp = (e & 31) * 2;
    uint2 v;
    v.x = lds[cp * 57 + w];
    v.y = lds[(cp + 1) * 57 + w];
    *reinterpret_cast<uint2*>(dst + (long)w * CIN + cp) = v;
  }
}

// zero the 1-pixel halo of xq (228 border cells per batch image)
__global__ void halo_zero(uint32_t* __restrict__ xq) {
  long idx = (long)blockIdx.x * 256 + threadIdx.x;
  if (idx >= (long)NB * 228 * CIN) return;
  int cin = (int)(idx & 255);
  long rem = idx >> 8;
  int b  = (int)(rem / 228);
  int pb = (int)(rem % 228);
  int hp, wp;
  if (pb < 58)       { hp = 0;  wp = pb; }
  else if (pb < 116) { hp = 57; wp = pb - 58; }
  else { int k = pb - 116; hp = 1 + (k >> 1); wp = (k & 1) * 57; }
  xq[(((long)b * WPAD + hp) * WPAD + wp) * CIN + cin] = 0u;
}

__device__ __forceinline__ long pad_off(int p) {   // bytes to x_pad[b][h][w][0] (r=(0,0) tap)
  int b = p / HW2;
  int hw = p % HW2;
  int h = hw / WW;
  int w = hw % WW;
  return ((long)((b * WPAD + h) * WPAD + w)) << 10;  // *256ch*4B
}

// One K-tile: 9 ds_read_b128, stage tile kt+2 (per-wave role), 14 MFMA, counted vmcnt, 1 barrier.
// Waves: 0/1 stage A rows [0,64)/[64,128) (4 gloads); 2 stages B rows [0,64) (4); 3 rows [64,112) (3).
// ENDW: 1 = counted per-wave vmcnt(nst); 0 = drain; -1 = none.
template<int RB, int SB, int STG, int ENDW>
__device__ __forceinline__ void tile_step(char* smem, int wv, int nst, int aoff, int boff, int dof,
    const char* sg0, const char* sg1, const char* sg2, const char* sg3,
    f32x4 (&acc)[2][7]) {
  const char* Ab = smem + ABUF(RB) + aoff;
  const char* Bb = smem + BBUF(RB) + boff;
  half8 af0 = *(const half8*)(Ab);
  half8 af1 = *(const half8*)(Ab + 1024);
  half8 bf[7];
  #pragma unroll
  for (int nf = 0; nf < 7; ++nf) bf[nf] = *(const half8*)(Bb + nf * 1024);
  if (STG) {
    char* db = (wv < 2 ? smem + ABUF(SB) : smem + BBUF(SB)) + dof;
    gload16(sg0, db);
    gload16(sg1, db + 1024);
    gload16(sg2, db + 2048);
    if (nst == 4) gload16(sg3, db + 3072);
  }
  WAIT_LGKM0();
  __builtin_amdgcn_s_setprio(1);
  #pragma unroll
  for (int nf = 0; nf < 7; ++nf) {
    acc[0][nf] = __builtin_amdgcn_mfma_f32_16x16x32_f16(af0, bf[nf], acc[0][nf], 0, 0, 0);
    acc[1][nf] = __builtin_amdgcn_mfma_f32_16x16x32_f16(af1, bf[nf], acc[1][nf], 0, 0, 0);
  }
  __builtin_amdgcn_s_setprio(0);
  if constexpr (ENDW == 1) {
    if (nst == 4) { asm volatile("s_waitcnt vmcnt(4)" ::: "memory"); }
    else          { asm volatile("s_waitcnt vmcnt(3)" ::: "memory"); }
    __builtin_amdgcn_sched_barrier(0);
  } else if constexpr (ENDW == 0) {
    asm volatile("s_waitcnt vmcnt(0)" ::: "memory");
    __builtin_amdgcn_sched_barrier(0);
  }
  BAR();
}

// ---------- implicit-GEMM conv: 128(cout) x 112(pix) tile, 4 waves, 3-buf depth-2 pipeline ----------
// Grid 1792 = 7 blocks/CU exact (no tail rounds); 45KB LDS -> 3 blocks/CU co-resident.
// T2 chunk-XOR swizzle kept from round 5 (bank conflicts measured 0).
__global__ __launch_bounds__(256, 3) void gemm_conv(
    const uint32_t* __restrict__ xq, const uint16_t* __restrict__ Wd,
    const float* __restrict__ bias, float* __restrict__ out) {
  int orig = blockIdx.x;                       // 1792 = 8 * 224
  int bi = (orig & 7) * 224 + (orig >> 3);     // XCD-bijective swizzle
  int ct = bi & 1, pt = bi >> 1;               // cout half, pixel tile 0..895
  int cout0 = ct * 128, pix0 = pt * 112;
  int t = threadIdx.x, wv = t >> 6, lane = t & 63;
  int nst = (wv == 3) ? 3 : 4;

  __shared__ __align__(1024) char smem[46080];

  // staging sources: lane l covers row base+(l>>2), swizzled chunk (l&3)^((l>>3)&3)
  int srow = (wv & 1) * 64 + (lane >> 2);
  int sb   = (((lane & 3) ^ ((lane >> 3) & 3)) * 16);
  int dof  = (wv & 1) * 4096;                  // wave-uniform LDS dest offset
  const char* wdc = (const char*)Wd;
  const char* xqc = (const char*)xq;
  const char *sg0, *sg1, *sg2, *sg3;
  if (wv < 2) {
    sg0 = wdc + (long)(cout0 + srow +  0) * 9216 + sb;
    sg1 = wdc + (long)(cout0 + srow + 16) * 9216 + sb;
    sg2 = wdc + (long)(cout0 + srow + 32) * 9216 + sb;
    sg3 = wdc + (long)(cout0 + srow + 48) * 9216 + sb;
  } else {
    sg0 = xqc + pad_off(pix0 + srow +  0) + sb;
    sg1 = xqc + pad_off(pix0 + srow + 16) + sb;
    sg2 = xqc + pad_off(pix0 + srow + 32) + sb;
    sg3 = (wv == 3) ? sg2 : (xqc + pad_off(pix0 + srow + 48) + sb);  // w3 never issues g=3
  }

  // fragment reads: compensating slot XOR (validated round 5: conflicts = 0)
  int r15  = lane & 15;
  int slot = (lane >> 4) ^ ((r15 >> 1) & 3);
  int aoff = (wv * 32 + r15) * 64 + slot * 16;
  int boff = r15 * 64 + slot * 16;

  f32x4 acc[2][7] = {};

  int st = 0;  // tiles staged so far; B sources jump entering tap-rows 1,2
  auto stepk = [&]() {
    sg0 += 64; sg1 += 64; sg2 += 64; sg3 += 64; ++st;
    if (wv >= 2 && (st == 48 || st == 96)) {
      sg0 += 56320; sg1 += 56320; sg2 += 56320; sg3 += 56320;  // 58*1024 - 48*64
    }
  };
  auto stageT = [&](int SB_) {
    char* db = (wv < 2 ? smem + ABUF(SB_) : smem + BBUF(SB_)) + dof;
    gload16(sg0, db);
    gload16(sg1, db + 1024);
    gload16(sg2, db + 2048);
    if (nst == 4) gload16(sg3, db + 3072);
  };

  // prologue: stage tiles 0,1; wait tile 0 landed (tile 1's loads stay in flight)
  stageT(0); stepk();
  stageT(1); stepk();
  if (nst == 4) { asm volatile("s_waitcnt vmcnt(4)" ::: "memory"); }
  else          { asm volatile("s_waitcnt vmcnt(3)" ::: "memory"); }
  __builtin_amdgcn_sched_barrier(0);
  BAR();

  // main loop: kt = 0..140 (47 x 3 static rotation), then peel 141..143
  #pragma unroll 1
  for (int it = 0; it < 47; ++it) {
    tile_step<0, 2, 1, 1>(smem, wv, nst, aoff, boff, dof, sg0, sg1, sg2, sg3, acc); stepk();
    tile_step<1, 0, 1, 1>(smem, wv, nst, aoff, boff, dof, sg0, sg1, sg2, sg3, acc); stepk();
    tile_step<2, 1, 1, 1>(smem, wv, nst, aoff, boff, dof, sg0, sg1, sg2, sg3, acc); stepk();
  }
  tile_step<0, 2, 1, 1>(smem, wv, nst, aoff, boff, dof, sg0, sg1, sg2, sg3, acc); stepk();  // kt=141
  tile_step<1, 0, 0, 0>(smem, wv, nst, aoff, boff, dof, sg0, sg1, sg2, sg3, acc);           // kt=142
  tile_step<2, 0, 0, -1>(smem, wv, nst, aoff, boff, dof, sg0, sg1, sg2, sg3, acc);          // kt=143

  // epilogue: D row = cout (m89 layout), col = pixel; 112 | 3136 so no batch-crossing
  int rg4  = (lane >> 4) * 4;
  int colp = lane & 15;
  float bq[2][4];
  #pragma unroll
  for (int mf = 0; mf < 2; ++mf) {
    f32x4 bv = *(const f32x4*)(bias + cout0 + wv * 32 + mf * 16 + rg4);
    #pragma unroll
    for (int r2 = 0; r2 < 4; ++r2) bq[mf][r2] = quant_fixed(bv[r2]);
  }
  int bimg = pt / 28;
  int hw0  = (pt % 28) * 112;
  long ob  = (long)bimg * (COUT * HW2);
  #pragma unroll
  for (int nf = 0; nf < 7; ++nf) {
    int hw = hw0 + nf * 16 + colp;
    #pragma unroll
    for (int mf = 0; mf < 2; ++mf) {
      int cg = cout0 + wv * 32 + mf * 16 + rg4;
      #pragma unroll
      for (int r2 = 0; r2 < 4; ++r2)
        out[ob + (long)(cg + r2) * HW2 + hw] = acc[mf][nf][r2] + bq[mf][r2];
    }
  }
}

// ---------- fallback direct conv (only if workspace too small) ----------
__global__ void conv_direct(const float* __restrict__ in, const float* __restrict__ vw,
                            const float* __restrict__ bias, float* __restrict__ out) {
  long idx = (long)blockIdx.x * 256 + threadIdx.x;
  if (idx >= (long)NB * COUT * HW2) return;
  int hw = (int)(idx % HW2);
  int t2 = (int)(idx / HW2);
  int co = t2 & 255, b = t2 >> 8;
  int h = hw / WW, w = hw % WW;
  float acc = quant_fixed(bias[co]);
  const float* inb = in + (long)b * CIN * HW2;
  const float* vwc = vw + (long)co * CIN * 9;
  for (int ci = 0; ci < CIN; ci++) {
    const float* xp = inb + (long)ci * HW2;
    const float* vp = vwc + ci * 9;
    #pragma unroll
    for (int kh = 0; kh < 3; kh++) {
      int hy = h + kh - 1;
      if ((unsigned)hy >= HH) continue;
      #pragma unroll
      for (int kw = 0; kw < 3; kw++) {
        int wx = w + kw - 1;
        if ((unsigned)wx >= WW) continue;
        acc += quant_fixed(xp[hy * WW + wx]) * vp[kh * 3 + kw];
      }
    }
  }
  out[idx] = acc;
}

extern "C" void kernel_launch(void* const* d_in, const int* in_sizes, int n_in,
                              void* d_out, int out_size, void* d_ws, size_t ws_size,
                              hipStream_t stream) {
  const float* input = (const float*)d_in[0];
  const float* shift = (const float*)d_in[1];
  const float* sgn   = (const float*)d_in[2];
  const float* bias  = (const float*)d_in[3];
  float* out = (float*)d_out;

  if (ws_size >= (size_t)(XQ_BYTES + WD_BYTES)) {
    uint32_t* xq = (uint32_t*)d_ws;
    uint16_t* Wd = (uint16_t*)((char*)d_ws + XQ_BYTES);
    prep_w<<<2304, 256, 0, stream>>>(shift, sgn, (uint32_t*)Wd);
    prep_x<<<dim3(4, 56, 32), 256, 0, stream>>>(input, xq);
    halo_zero<<<7296, 256, 0, stream>>>(xq);
    gemm_conv<<<1792, 256, 0, stream>>>(xq, Wd, bias, out);
  } else {
    float* vw = (float*)d_ws;
    prep_w_f32<<<2304, 256, 0, stream>>>(shift, sgn, vw);
    conv_direct<<<100352, 256, 0, stream>>>(input, vw, bias, out);
  }
}

// Round 8
// 434.121 us; speedup vs baseline: 1.0787x; 1.0787x over previous
//
#include <hip/hip_runtime.h>
#include <stdint.h>

typedef _Float16 half8 __attribute__((ext_vector_type(8)));
typedef float f32x4 __attribute__((ext_vector_type(4)));

#define CIN   256
#define COUT  256
#define NB    32
#define HH    56
#define WW    56
#define WPAD  58
#define HW2   3136            // 56*56
#define KHALF 4608            // 9 * 256 * 2 (hi/lo interleaved)
#define NKT   144             // K-tiles of 32 halves (64B)
#define XQ_BYTES 110231552L   // 32*58*58*256*4
#define WD_BYTES 2359296L     // 256*4608*2

// LDS: 3 A-buffers (256 rows x 64B = 16KB) + 3 B-buffers -> 96KB, 1 block/CU
#define ABUF(i) ((i) * 16384)
#define BBUF(i) (49152 + (i) * 16384)

__device__ __forceinline__ float quant_fixed(float x) {
  float q = floorf(x * 65536.0f) * (1.0f / 65536.0f);
  return fminf(fmaxf(q, -32768.0f), 32767.0f);
}

__device__ __forceinline__ void gload16(const void* g, void* l) {
  __builtin_amdgcn_global_load_lds(
      (const __attribute__((address_space(1))) void*)g,
      (__attribute__((address_space(3))) void*)l, 16, 0, 0);
}

#define SBAR() __builtin_amdgcn_sched_barrier(0)
#define BAR() __builtin_amdgcn_s_barrier()

// ---------- weight prep: Wd[cout][k], k = r*512 + cin*2 + {hi,lo}, both slots = v ----------
__global__ void prep_w(const float* __restrict__ shift, const float* __restrict__ sgn,
                       uint32_t* __restrict__ Wd32) {
  int o = blockIdx.x * 256 + threadIdx.x;       // o = cout*2304 + r*256 + cin
  if (o >= COUT * 2304) return;
  int cout = o / 2304;
  int rem  = o % 2304;
  int r    = rem >> 8;
  int cin  = rem & 255;
  int idx  = cout * 2304 + cin * 9 + r;         // OIHW source index
  float s  = rintf(fminf(fmaxf(shift[idx], -14.0f), 0.0f));
  float sg = rintf(sgn[idx]);
  float v  = (sg > 0.0f ? 1.0f : (sg < 0.0f ? -1.0f : 0.0f)) * exp2f(s);
  _Float16 vh = (_Float16)v;
  uint16_t u = __builtin_bit_cast(uint16_t, vh);
  Wd32[o] = ((uint32_t)u << 16) | u;
}

// fp32 weights in OIHW order (fallback path only)
__global__ void prep_w_f32(const float* __restrict__ shift, const float* __restrict__ sgn,
                           float* __restrict__ vw) {
  int idx = blockIdx.x * 256 + threadIdx.x;
  if (idx >= COUT * CIN * 9) return;
  float s  = rintf(fminf(fmaxf(shift[idx], -14.0f), 0.0f));
  float sg = rintf(sgn[idx]);
  vw[idx]  = (sg > 0.0f ? 1.0f : (sg < 0.0f ? -1.0f : 0.0f)) * exp2f(s);
}

// ---------- activation prep: NCHW fp32 -> padded NHWC uint32 (lo<<16 | hi fp16 pair) ----------
__global__ void prep_x(const float* __restrict__ in, uint32_t* __restrict__ xq) {
  int cinblk = blockIdx.x;   // 0..3  (64 channels each)
  int h      = blockIdx.y;   // 0..55
  int b      = blockIdx.z;   // 0..31
  int t      = threadIdx.x;  // 256
  __shared__ uint32_t lds[64 * 57];
  const float* src = in + ((long)(b * CIN + cinblk * 64)) * HW2 + h * WW;
  #pragma unroll
  for (int i = 0; i < 7; i++) {            // 64ch * 28 wpairs = 1792 = 7*256
    int e = t + i * 256;
    int cin = e / 28, w = (e % 28) * 2;
    float2 x2 = *reinterpret_cast<const float2*>(src + (long)cin * HW2 + w);
    float q0 = quant_fixed(x2.x), q1 = quant_fixed(x2.y);
    _Float16 h0 = (_Float16)q0, l0 = (_Float16)(q0 - (float)h0);
    _Float16 h1 = (_Float16)q1, l1 = (_Float16)(q1 - (float)h1);
    lds[cin * 57 + w]     = ((uint32_t)__builtin_bit_cast(uint16_t, l0) << 16)
                           | __builtin_bit_cast(uint16_t, h0);
    lds[cin * 57 + w + 1] = ((uint32_t)__builtin_bit_cast(uint16_t, l1) << 16)
                           | __builtin_bit_cast(uint16_t, h1);
  }
  __syncthreads();
  uint32_t* dst = xq + ((long)(b * WPAD + h + 1) * WPAD + 1) * CIN + cinblk * 64;
  #pragma unroll
  for (int i = 0; i < 7; i++) {            // 56 w * 32 cpairs = 1792
    int e = t + i * 256;
    int w = e >> 5, cp = (e & 31) * 2;
    uint2 v;
    v.x = lds[cp * 57 + w];
    v.y = lds[(cp + 1) * 57 + w];
    *reinterpret_cast<uint2*>(dst + (long)w * CIN + cp) = v;
  }
}

// zero the 1-pixel halo of xq (228 border cells per batch image)
__global__ void halo_zero(uint32_t* __restrict__ xq) {
  long idx = (long)blockIdx.x * 256 + threadIdx.x;
  if (idx >= (long)NB * 228 * CIN) return;
  int cin = (int)(idx & 255);
  long rem = idx >> 8;
  int b  = (int)(rem / 228);
  int pb = (int)(rem % 228);
  int hp, wp;
  if (pb < 58)       { hp = 0;  wp = pb; }
  else if (pb < 116) { hp = 57; wp = pb - 58; }
  else { int k = pb - 116; hp = 1 + (k >> 1); wp = (k & 1) * 57; }
  xq[(((long)b * WPAD + hp) * WPAD + wp) * CIN + cin] = 0u;
}

__device__ __forceinline__ long pad_off(int p) {   // bytes to x_pad[b][h][w][0] (r=(0,0) tap)
  int b = p / HW2;
  int hw = p % HW2;
  int h = hw / WW;
  int w = hw % WW;
  return ((long)((b * WPAD + h) * WPAD + w)) << 10;  // *256ch*4B
}

// stage one full K-tile (A0,A1,B0,B1 halves) — prologue only
template<int SB>
__device__ __forceinline__ void stage4(char* smem, int wv,
    const char* sA0, const char* sA1, const char* sB0, const char* sB1) {
  gload16(sA0, smem + ABUF(SB) + wv * 1024);
  gload16(sA1, smem + ABUF(SB) + 8192 + wv * 1024);
  gload16(sB0, smem + BBUF(SB) + wv * 1024);
  gload16(sB1, smem + BBUF(SB) + 8192 + wv * 1024);
}

// One K-tile (BK=32 halves), SINGLE-PHASE schedule with counted waits (m201-style):
//   issue 8 first-needed ds_reads | SBAR | issue 4 more ds_reads | stage-A(kt+2)
//   lgkmcnt(4)  -> af[0..3],bf[0..3] ready, af[4..7] still in flight under MFMAs
//   16 MFMA (m-half0) | stage-B(kt+2) | lgkmcnt(0) (free) | 16 MFMA (m-half1)
//   vmcnt(4) (keep kt+2's 4 stages in flight) | ONE barrier.
// Race-freedom: mod-3 rotation + 1 barrier/tile bounds wave skew <1 tile, so the
// read buffer is never the staged buffer; per-wave vmcnt(4) before the barrier
// publishes kt+1's data. DS ops complete in-order per wave (counted lgkm sound;
// if b128 splits into b64 pairs the wait only becomes stricter).
template<int RB, int SB, int STG, int ENDW>
__device__ __forceinline__ void tile_step(char* smem, int wv, int aoff, int boff,
    const char* sA0, const char* sA1, const char* sB0, const char* sB1,
    f32x4 (&acc)[8][4]) {
  const char* Ab = smem + ABUF(RB) + aoff;
  const char* Bb = smem + BBUF(RB) + boff;
  half8 bf[4], af[8];
  // group 1: the 8 reads cluster0 needs
  #pragma unroll
  for (int j = 0; j < 4; ++j) af[j] = *(const half8*)(Ab + j * 1024);
  #pragma unroll
  for (int nf = 0; nf < 4; ++nf) bf[nf] = *(const half8*)(Bb + nf * 1024);
  SBAR();   // pin: group-2 reads must stay AFTER group-1 (counted lgkm relies on order)
  // group 2: m-half1 A-frags (consumed by cluster1)
  #pragma unroll
  for (int j = 0; j < 4; ++j) af[4 + j] = *(const half8*)(Ab + 4096 + j * 1024);
  if (STG) {
    gload16(sA0, smem + ABUF(SB) + wv * 1024);
    gload16(sA1, smem + ABUF(SB) + 8192 + wv * 1024);
  }
  asm volatile("s_waitcnt lgkmcnt(4)" ::: "memory");   // group-1 landed
  SBAR();
  __builtin_amdgcn_s_setprio(1);
  #pragma unroll
  for (int j = 0; j < 4; ++j)
    #pragma unroll
    for (int nf = 0; nf < 4; ++nf)
      acc[j][nf] = __builtin_amdgcn_mfma_f32_16x16x32_f16(af[j], bf[nf], acc[j][nf], 0, 0, 0);
  __builtin_amdgcn_s_setprio(0);
  if (STG) {
    gload16(sB0, smem + BBUF(SB) + wv * 1024);
    gload16(sB1, smem + BBUF(SB) + 8192 + wv * 1024);
  }
  asm volatile("s_waitcnt lgkmcnt(0)" ::: "memory");   // group-2 (issued long ago)
  SBAR();
  __builtin_amdgcn_s_setprio(1);
  #pragma unroll
  for (int j = 0; j < 4; ++j)
    #pragma unroll
    for (int nf = 0; nf < 4; ++nf)
      acc[4 + j][nf] = __builtin_amdgcn_mfma_f32_16x16x32_f16(af[4 + j], bf[nf], acc[4 + j][nf], 0, 0, 0);
  __builtin_amdgcn_s_setprio(0);
  if constexpr (ENDW == 4) {
    asm volatile("s_waitcnt vmcnt(4)" ::: "memory");
    SBAR();
  } else if constexpr (ENDW == 0) {
    asm volatile("s_waitcnt vmcnt(0)" ::: "memory");
    SBAR();
  }
  BAR();   // the ONLY barrier per K-tile
}

// ---------- implicit-GEMM conv: 256(cout) x 256(pix) tile, 8 waves, 3-buf depth-2 pipeline ----------
// T2 chunk-XOR swizzle (validated round 5: bank conflicts = 0).
__global__ __launch_bounds__(512, 2) void gemm_conv(
    const uint32_t* __restrict__ xq, const uint16_t* __restrict__ Wd,
    const float* __restrict__ bias, float* __restrict__ out) {
  int orig = blockIdx.x;                       // 392 = 8 * 49
  int bi = (orig & 7) * 49 + (orig >> 3);      // XCD-bijective swizzle
  int pix0 = bi << 8;
  int t = threadIdx.x, wv = t >> 6, lane = t & 63;
  int wm = wv >> 2, wn = wv & 3;               // wave grid 2(M) x 4(N)

  __shared__ __align__(1024) char smem[98304];

  // staging: lane l stages global chunk (l&3)^((l>>3)&3) of row wv*16+(l>>2)
  // into LDS linear slot l&3  => LDS slot c holds logical chunk c^((row>>1)&3)
  int srow = wv * 16 + (lane >> 2);
  int sb   = (((lane & 3) ^ ((lane >> 3) & 3)) * 16);
  const char* wdc = (const char*)Wd;
  const char* xqc = (const char*)xq;
  const char* sA0 = wdc + (long)srow * 9216 + sb;            // cout rows 0..127
  const char* sA1 = wdc + (long)(srow + 128) * 9216 + sb;    // cout rows 128..255
  const char* sB0 = xqc + pad_off(pix0 + srow) + sb;         // pixel rows 0..127
  const char* sB1 = xqc + pad_off(pix0 + srow + 128) + sb;   // pixel rows 128..255

  // fragment reads: logical k-chunk s=lane>>4 lives at slot s^(((lane&15)>>1)&3)
  int r15  = lane & 15;
  int slot = (lane >> 4) ^ ((r15 >> 1) & 3);
  int aoff = (wm * 128 + r15) * 64 + slot * 16;
  int boff = (wn * 64 + r15) * 64 + slot * 16;

  f32x4 acc[8][4] = {};

  int st = 0;  // tiles staged so far; B makes a row jump entering tap-rows 1,2
  auto step = [&]() {
    sA0 += 64; sA1 += 64; sB0 += 64; sB1 += 64; ++st;
    if (st == 48 || st == 96) { sB0 += 56320; sB1 += 56320; }  // 58*1024 - 48*64
  };

  // prologue: stage tiles 0,1; wait tile 0 landed (keep tile 1's 4 loads in flight)
  stage4<0>(smem, wv, sA0, sA1, sB0, sB1); step();
  stage4<1>(smem, wv, sA0, sA1, sB0, sB1); step();
  asm volatile("s_waitcnt vmcnt(4)" ::: "memory");
  SBAR();
  BAR();

  // main loop: 141 tiles (47 x 3 for static buffer rotation), then peel 141..143
  #pragma unroll 1
  for (int it = 0; it < 47; ++it) {
    tile_step<0, 2, 1, 4>(smem, wv, aoff, boff, sA0, sA1, sB0, sB1, acc); step();
    tile_step<1, 0, 1, 4>(smem, wv, aoff, boff, sA0, sA1, sB0, sB1, acc); step();
    tile_step<2, 1, 1, 4>(smem, wv, aoff, boff, sA0, sA1, sB0, sB1, acc); step();
  }
  tile_step<0, 2, 1, 4>(smem, wv, aoff, boff, sA0, sA1, sB0, sB1, acc); step();  // kt=141
  tile_step<1, 0, 0, 0>(smem, wv, aoff, boff, sA0, sA1, sB0, sB1, acc);          // kt=142
  tile_step<2, 0, 0, -1>(smem, wv, aoff, boff, sA0, sA1, sB0, sB1, acc);         // kt=143

  // epilogue: D row = cout = wm*128 + mf*16 + (lane>>4)*4 + r2, col = pixel (m89 layout)
  int rg4  = (lane >> 4) * 4;
  int colp = lane & 15;
  float bq[8][4];
  #pragma unroll
  for (int mf = 0; mf < 8; ++mf) {
    f32x4 bv = *(const f32x4*)(bias + wm * 128 + mf * 16 + rg4);
    #pragma unroll
    for (int r2 = 0; r2 < 4; ++r2) bq[mf][r2] = quant_fixed(bv[r2]);
  }
  #pragma unroll
  for (int nf = 0; nf < 4; ++nf) {
    int pg = pix0 + wn * 64 + nf * 16 + colp;
    int b  = pg / HW2;
    int hw = pg % HW2;
    long ob = (long)b * (COUT * HW2) + hw;
    #pragma unroll
    for (int mf = 0; mf < 8; ++mf) {
      int cg = wm * 128 + mf * 16 + rg4;
      #pragma unroll
      for (int r2 = 0; r2 < 4; ++r2)
        out[ob + (long)(cg + r2) * HW2] = acc[mf][nf][r2] + bq[mf][r2];
    }
  }
}

// ---------- fallback direct conv (only if workspace too small) ----------
__global__ void conv_direct(const float* __restrict__ in, const float* __restrict__ vw,
                            const float* __restrict__ bias, float* __restrict__ out) {
  long idx = (long)blockIdx.x * 256 + threadIdx.x;
  if (idx >= (long)NB * COUT * HW2) return;
  int hw = (int)(idx % HW2);
  int t2 = (int)(idx / HW2);
  int co = t2 & 255, b = t2 >> 8;
  int h = hw / WW, w = hw % WW;
  float acc = quant_fixed(bias[co]);
  const float* inb = in + (long)b * CIN * HW2;
  const float* vwc = vw + (long)co * CIN * 9;
  for (int ci = 0; ci < CIN; ci++) {
    const float* xp = inb + (long)ci * HW2;
    const float* vp = vwc + ci * 9;
    #pragma unroll
    for (int kh = 0; kh < 3; kh++) {
      int hy = h + kh - 1;
      if ((unsigned)hy >= HH) continue;
      #pragma unroll
      for (int kw = 0; kw < 3; kw++) {
        int wx = w + kw - 1;
        if ((unsigned)wx >= WW) continue;
        acc += quant_fixed(xp[hy * WW + wx]) * vp[kh * 3 + kw];
      }
    }
  }
  out[idx] = acc;
}

extern "C" void kernel_launch(void* const* d_in, const int* in_sizes, int n_in,
                              void* d_out, int out_size, void* d_ws, size_t ws_size,
                              hipStream_t stream) {
  const float* input = (const float*)d_in[0];
  const float* shift = (const float*)d_in[1];
  const float* sgn   = (const float*)d_in[2];
  const float* bias  = (const float*)d_in[3];
  float* out = (float*)d_out;

  if (ws_size >= (size_t)(XQ_BYTES + WD_BYTES)) {
    uint32_t* xq = (uint32_t*)d_ws;
    uint16_t* Wd = (uint16_t*)((char*)d_ws + XQ_BYTES);
    prep_w<<<2304, 256, 0, stream>>>(shift, sgn, (uint32_t*)Wd);
    prep_x<<<dim3(4, 56, 32), 256, 0, stream>>>(input, xq);
    halo_zero<<<7296, 256, 0, stream>>>(xq);
    gemm_conv<<<392, 512, 0, stream>>>(xq, Wd, bias, out);
  } else {
    float* vw = (float*)d_ws;
    prep_w_f32<<<2304, 256, 0, stream>>>(shift, sgn, vw);
    conv_direct<<<100352, 256, 0, stream>>>(input, vw, bias, out);
  }
}

// Round 9
// 338.032 us; speedup vs baseline: 1.3853x; 1.2843x over previous
//
#include <hip/hip_runtime.h>
#include <stdint.h>

typedef _Float16 half8 __attribute__((ext_vector_type(8)));
typedef float f32x4 __attribute__((ext_vector_type(4)));

#define CIN   256
#define COUT  256
#define NB    32
#define HH    56
#define WW    56
#define WPAD  58
#define HW2   3136            // 56*56
#define KEL   2304            // 9 * 256 f16 elements (single-piece activations)
#define NKT   72              // K-tiles of 32 f16 (64B rows)
#define XQ_BYTES 55115776L    // 32*58*58*256*2
#define WD_BYTES 1179648L     // 256*2304*2

// LDS: 3 A-buffers (256 rows x 64B = 16KB) + 3 B-buffers -> 96KB, 1 block/CU
#define ABUF(i) ((i) * 16384)
#define BBUF(i) (49152 + (i) * 16384)

__device__ __forceinline__ float quant_fixed(float x) {
  float q = floorf(x * 65536.0f) * (1.0f / 65536.0f);
  return fminf(fmaxf(q, -32768.0f), 32767.0f);
}

__device__ __forceinline__ void gload16(const void* g, void* l) {
  __builtin_amdgcn_global_load_lds(
      (const __attribute__((address_space(1))) void*)g,
      (__attribute__((address_space(3))) void*)l, 16, 0, 0);
}

#define SBAR() __builtin_amdgcn_sched_barrier(0)
#define BAR() __builtin_amdgcn_s_barrier()

// ---------- weight prep: Wd[cout][k], k = r*256 + cin (f16, no duplication) ----------
__global__ void prep_w(const float* __restrict__ shift, const float* __restrict__ sgn,
                       uint32_t* __restrict__ Wd32) {
  int o2 = blockIdx.x * 256 + threadIdx.x;      // packs 2 cin per thread
  if (o2 >= COUT * 1152) return;
  int cout = o2 / 1152;
  int rem  = o2 % 1152;
  int r    = rem >> 7;
  int cp   = (rem & 127) * 2;
  uint16_t u[2];
  #pragma unroll
  for (int i = 0; i < 2; ++i) {
    int idx  = cout * 2304 + (cp + i) * 9 + r;  // OIHW source
    float s  = rintf(fminf(fmaxf(shift[idx], -14.0f), 0.0f));
    float sg = rintf(sgn[idx]);
    float v  = (sg > 0.0f ? 1.0f : (sg < 0.0f ? -1.0f : 0.0f)) * exp2f(s);
    _Float16 vh = (_Float16)v;                  // +/-2^s, s>=-14: exact f16 normal
    u[i] = __builtin_bit_cast(uint16_t, vh);
  }
  Wd32[o2] = ((uint32_t)u[1] << 16) | u[0];
}

// fp32 weights in OIHW order (fallback path only)
__global__ void prep_w_f32(const float* __restrict__ shift, const float* __restrict__ sgn,
                           float* __restrict__ vw) {
  int idx = blockIdx.x * 256 + threadIdx.x;
  if (idx >= COUT * CIN * 9) return;
  float s  = rintf(fminf(fmaxf(shift[idx], -14.0f), 0.0f));
  float sg = rintf(sgn[idx]);
  vw[idx]  = (sg > 0.0f ? 1.0f : (sg < 0.0f ? -1.0f : 0.0f)) * exp2f(s);
}

// ---------- activation prep: NCHW fp32 -> padded NHWC f16 (single piece) ----------
// thread reads 2 consecutive cin at one w (coalesced over w), packs u32 = 2 f16
__global__ void prep_x(const float* __restrict__ in, uint32_t* __restrict__ xq32) {
  int cinblk = blockIdx.x;   // 0..3  (64 channels each)
  int h      = blockIdx.y;   // 0..55
  int b      = blockIdx.z;   // 0..31
  int t      = threadIdx.x;  // 256
  __shared__ uint32_t lds[32 * 57];            // [cinpair][w]
  const float* src = in + ((long)(b * CIN + cinblk * 64)) * HW2 + h * WW;
  #pragma unroll
  for (int i = 0; i < 7; i++) {                // 32 cpairs * 56 w = 1792 = 7*256
    int e = t + i * 256;
    int cp = e / 56, w = e % 56;
    float x0 = src[(long)(cp * 2) * HW2 + w];
    float x1 = src[(long)(cp * 2 + 1) * HW2 + w];
    _Float16 f0 = (_Float16)quant_fixed(x0);
    _Float16 f1 = (_Float16)quant_fixed(x1);
    lds[cp * 57 + w] = ((uint32_t)__builtin_bit_cast(uint16_t, f1) << 16)
                      | __builtin_bit_cast(uint16_t, f0);
  }
  __syncthreads();
  // dst u32 layout: [w][cpair] within this 64-ch slice
  uint32_t* dst = xq32 + ((long)(b * WPAD + h + 1) * WPAD + 1) * 128 + cinblk * 32;
  #pragma unroll
  for (int i = 0; i < 7; i++) {
    int e = t + i * 256;
    int w = e >> 5, cp = e & 31;               // 56 w * 32 cpairs
    dst[(long)w * 128 + cp] = lds[cp * 57 + w];
  }
}

// zero the 1-pixel halo of xq (228 border cells per batch image; 128 u32 per cell)
__global__ void halo_zero(uint32_t* __restrict__ xq32) {
  long idx = (long)blockIdx.x * 256 + threadIdx.x;
  if (idx >= (long)NB * 228 * 128) return;
  int c32 = (int)(idx & 127);
  long rem = idx >> 7;
  int b  = (int)(rem / 228);
  int pb = (int)(rem % 228);
  int hp, wp;
  if (pb < 58)       { hp = 0;  wp = pb; }
  else if (pb < 116) { hp = 57; wp = pb - 58; }
  else { int k = pb - 116; hp = 1 + (k >> 1); wp = (k & 1) * 57; }
  xq32[(((long)b * WPAD + hp) * WPAD + wp) * 128 + c32] = 0u;
}

__device__ __forceinline__ long pad_off(int p) {   // bytes to x_pad[b][h][w][0] (512B/pixel)
  int b = p / HW2;
  int hw = p % HW2;
  int h = hw / WW;
  int w = hw % WW;
  return ((long)((b * WPAD + h) * WPAD + w)) << 9;   // *256ch*2B
}

// stage one full K-tile (A0,A1,B0,B1 halves) — prologue only
template<int SB>
__device__ __forceinline__ void stage4(char* smem, int wv,
    const char* sA0, const char* sA1, const char* sB0, const char* sB1) {
  gload16(sA0, smem + ABUF(SB) + wv * 1024);
  gload16(sA1, smem + ABUF(SB) + 8192 + wv * 1024);
  gload16(sB0, smem + BBUF(SB) + wv * 1024);
  gload16(sB1, smem + BBUF(SB) + 8192 + wv * 1024);
}

// One K-tile (BK=32 f16), single-phase schedule with counted waits (round-8 validated):
//   12 ds_reads (8 first-needed | SBAR | 4 more) | stage-A(kt+2) | lgkmcnt(4)
//   16 MFMA | stage-B(kt+2) | lgkmcnt(0) | 16 MFMA | vmcnt(4) | ONE barrier.
template<int RB, int SB, int STG, int ENDW>
__device__ __forceinline__ void tile_step(char* smem, int wv, int aoff, int boff,
    const char* sA0, const char* sA1, const char* sB0, const char* sB1,
    f32x4 (&acc)[8][4]) {
  const char* Ab = smem + ABUF(RB) + aoff;
  const char* Bb = smem + BBUF(RB) + boff;
  half8 bf[4], af[8];
  #pragma unroll
  for (int j = 0; j < 4; ++j) af[j] = *(const half8*)(Ab + j * 1024);
  #pragma unroll
  for (int nf = 0; nf < 4; ++nf) bf[nf] = *(const half8*)(Bb + nf * 1024);
  SBAR();   // pin: group-2 reads stay AFTER group-1 (counted lgkm relies on order)
  #pragma unroll
  for (int j = 0; j < 4; ++j) af[4 + j] = *(const half8*)(Ab + 4096 + j * 1024);
  if (STG) {
    gload16(sA0, smem + ABUF(SB) + wv * 1024);
    gload16(sA1, smem + ABUF(SB) + 8192 + wv * 1024);
  }
  asm volatile("s_waitcnt lgkmcnt(4)" ::: "memory");
  SBAR();
  __builtin_amdgcn_s_setprio(1);
  #pragma unroll
  for (int j = 0; j < 4; ++j)
    #pragma unroll
    for (int nf = 0; nf < 4; ++nf)
      acc[j][nf] = __builtin_amdgcn_mfma_f32_16x16x32_f16(af[j], bf[nf], acc[j][nf], 0, 0, 0);
  __builtin_amdgcn_s_setprio(0);
  if (STG) {
    gload16(sB0, smem + BBUF(SB) + wv * 1024);
    gload16(sB1, smem + BBUF(SB) + 8192 + wv * 1024);
  }
  asm volatile("s_waitcnt lgkmcnt(0)" ::: "memory");
  SBAR();
  __builtin_amdgcn_s_setprio(1);
  #pragma unroll
  for (int j = 0; j < 4; ++j)
    #pragma unroll
    for (int nf = 0; nf < 4; ++nf)
      acc[4 + j][nf] = __builtin_amdgcn_mfma_f32_16x16x32_f16(af[4 + j], bf[nf], acc[4 + j][nf], 0, 0, 0);
  __builtin_amdgcn_s_setprio(0);
  if constexpr (ENDW == 4) {
    asm volatile("s_waitcnt vmcnt(4)" ::: "memory");
    SBAR();
  } else if constexpr (ENDW == 0) {
    asm volatile("s_waitcnt vmcnt(0)" ::: "memory");
    SBAR();
  }
  BAR();   // the ONLY barrier per K-tile
}

// ---------- implicit-GEMM conv: 256(cout) x 256(pix) tile, K=2304 f16, 8 waves ----------
// T2 chunk-XOR swizzle (validated: bank conflicts = 0).
__global__ __launch_bounds__(512, 2) void gemm_conv(
    const uint32_t* __restrict__ xq, const uint16_t* __restrict__ Wd,
    const float* __restrict__ bias, float* __restrict__ out) {
  int orig = blockIdx.x;                       // 392 = 8 * 49
  int bi = (orig & 7) * 49 + (orig >> 3);      // XCD-bijective swizzle
  int pix0 = bi << 8;
  int t = threadIdx.x, wv = t >> 6, lane = t & 63;
  int wm = wv >> 2, wn = wv & 3;               // wave grid 2(M) x 4(N)

  __shared__ __align__(1024) char smem[98304];

  // staging: lane l stages global chunk (l&3)^((l>>3)&3) of row wv*16+(l>>2)
  int srow = wv * 16 + (lane >> 2);
  int sb   = (((lane & 3) ^ ((lane >> 3) & 3)) * 16);
  const char* wdc = (const char*)Wd;
  const char* xqc = (const char*)xq;
  const char* sA0 = wdc + (long)srow * 4608 + sb;            // cout rows 0..127
  const char* sA1 = wdc + (long)(srow + 128) * 4608 + sb;    // cout rows 128..255
  const char* sB0 = xqc + pad_off(pix0 + srow) + sb;         // pixel rows 0..127
  const char* sB1 = xqc + pad_off(pix0 + srow + 128) + sb;   // pixel rows 128..255

  // fragment reads: logical k-chunk s=lane>>4 lives at slot s^(((lane&15)>>1)&3)
  int r15  = lane & 15;
  int slot = (lane >> 4) ^ ((r15 >> 1) & 3);
  int aoff = (wm * 128 + r15) * 64 + slot * 16;
  int boff = (wn * 64 + r15) * 64 + slot * 16;

  f32x4 acc[8][4] = {};

  int st = 0;  // staged-tile counter; B jumps to next tap ROW after taps 0-2 and 3-5
  auto step = [&]() {
    sA0 += 64; sA1 += 64; sB0 += 64; sB1 += 64; ++st;
    if (st == 24 || st == 48) { sB0 += 28160; sB1 += 28160; }  // 58*512 - 3*512
  };

  // prologue: stage tiles 0,1; wait tile 0 landed (tile 1's 4 loads stay in flight)
  stage4<0>(smem, wv, sA0, sA1, sB0, sB1); step();
  stage4<1>(smem, wv, sA0, sA1, sB0, sB1); step();
  asm volatile("s_waitcnt vmcnt(4)" ::: "memory");
  SBAR();
  BAR();

  // main loop: 69 tiles (23 x 3 static rotation), then peel 69..71
  #pragma unroll 1
  for (int it = 0; it < 23; ++it) {
    tile_step<0, 2, 1, 4>(smem, wv, aoff, boff, sA0, sA1, sB0, sB1, acc); step();
    tile_step<1, 0, 1, 4>(smem, wv, aoff, boff, sA0, sA1, sB0, sB1, acc); step();
    tile_step<2, 1, 1, 4>(smem, wv, aoff, boff, sA0, sA1, sB0, sB1, acc); step();
  }
  tile_step<0, 2, 1, 4>(smem, wv, aoff, boff, sA0, sA1, sB0, sB1, acc); step();  // kt=69
  tile_step<1, 0, 0, 0>(smem, wv, aoff, boff, sA0, sA1, sB0, sB1, acc);          // kt=70
  tile_step<2, 0, 0, -1>(smem, wv, aoff, boff, sA0, sA1, sB0, sB1, acc);         // kt=71

  // epilogue: D row = cout = wm*128 + mf*16 + (lane>>4)*4 + r2, col = pixel (m89 layout)
  int rg4  = (lane >> 4) * 4;
  int colp = lane & 15;
  float bq[8][4];
  #pragma unroll
  for (int mf = 0; mf < 8; ++mf) {
    f32x4 bv = *(const f32x4*)(bias + wm * 128 + mf * 16 + rg4);
    #pragma unroll
    for (int r2 = 0; r2 < 4; ++r2) bq[mf][r2] = quant_fixed(bv[r2]);
  }
  #pragma unroll
  for (int nf = 0; nf < 4; ++nf) {
    int pg = pix0 + wn * 64 + nf * 16 + colp;
    int b  = pg / HW2;
    int hw = pg % HW2;
    long ob = (long)b * (COUT * HW2) + hw;
    #pragma unroll
    for (int mf = 0; mf < 8; ++mf) {
      int cg = wm * 128 + mf * 16 + rg4;
      #pragma unroll
      for (int r2 = 0; r2 < 4; ++r2)
        out[ob + (long)(cg + r2) * HW2] = acc[mf][nf][r2] + bq[mf][r2];
    }
  }
}

// ---------- fallback direct conv (only if workspace too small) ----------
__global__ void conv_direct(const float* __restrict__ in, const float* __restrict__ vw,
                            const float* __restrict__ bias, float* __restrict__ out) {
  long idx = (long)blockIdx.x * 256 + threadIdx.x;
  if (idx >= (long)NB * COUT * HW2) return;
  int hw = (int)(idx % HW2);
  int t2 = (int)(idx / HW2);
  int co = t2 & 255, b = t2 >> 8;
  int h = hw / WW, w = hw % WW;
  float acc = quant_fixed(bias[co]);
  const float* inb = in + (long)b * CIN * HW2;
  const float* vwc = vw + (long)co * CIN * 9;
  for (int ci = 0; ci < CIN; ci++) {
    const float* xp = inb + (long)ci * HW2;
    const float* vp = vwc + ci * 9;
    #pragma unroll
    for (int kh = 0; kh < 3; kh++) {
      int hy = h + kh - 1;
      if ((unsigned)hy >= HH) continue;
      #pragma unroll
      for (int kw = 0; kw < 3; kw++) {
        int wx = w + kw - 1;
        if ((unsigned)wx >= WW) continue;
        acc += quant_fixed(xp[hy * WW + wx]) * vp[kh * 3 + kw];
      }
    }
  }
  out[idx] = acc;
}

extern "C" void kernel_launch(void* const* d_in, const int* in_sizes, int n_in,
                              void* d_out, int out_size, void* d_ws, size_t ws_size,
                              hipStream_t stream) {
  const float* input = (const float*)d_in[0];
  const float* shift = (const float*)d_in[1];
  const float* sgn   = (const float*)d_in[2];
  const float* bias  = (const float*)d_in[3];
  float* out = (float*)d_out;

  if (ws_size >= (size_t)(XQ_BYTES + WD_BYTES)) {
    uint32_t* xq = (uint32_t*)d_ws;
    uint16_t* Wd = (uint16_t*)((char*)d_ws + XQ_BYTES);
    prep_w<<<1152, 256, 0, stream>>>(shift, sgn, (uint32_t*)Wd);
    prep_x<<<dim3(4, 56, 32), 256, 0, stream>>>(input, xq);
    halo_zero<<<3648, 256, 0, stream>>>(xq);
    gemm_conv<<<392, 512, 0, stream>>>(xq, Wd, bias, out);
  } else {
    float* vw = (float*)d_ws;
    prep_w_f32<<<2304, 256, 0, stream>>>(shift, sgn, vw);
    conv_direct<<<100352, 256, 0, stream>>>(input, vw, bias, out);
  }
}